// Round 6
// baseline (190.946 us; speedup 1.0000x reference)
//
#include <hip/hip_runtime.h>

// Fused deformable-conv net, 4 images per 832-thread block (round-2 codegen
// shape + lane packing). tid<784 active: img_l=tid/196, cell=tid%196 ->
// 94.2% lane utilization vs round 2's 196/256=76.6%.
// Measured lessons enforced here:
//  - direct xs[int] LDS indexing (no float* row pointers)    [r2: 68VGPR/92%]
//  - no __launch_bounds__ min-waves arg                      [r4/r5: 44VGPR]
//  - no global atomics: butterfly -> LDS table -> 40 stores  [r4/r5: 5MB WRITE]

#define WP 30
#define NPOS 784
#define NPOOL 1568
#define CELLS 196
#define IPB 4                 // images per block
#define NTHR 832              // 13 waves; 784 active
#define NWAVE 13

__global__ __launch_bounds__(NTHR) void deform_net_kernel(
    const float* __restrict__ x,       // (B,1,28,28)
    const float* __restrict__ w_off,   // (18,1,3,3)
    const float* __restrict__ b_off,   // (18,)
    const float* __restrict__ w_conv,  // (8,1,3,3)
    const float* __restrict__ w_fc,    // (10,1568)
    const float* __restrict__ b_fc,    // (10,)
    float* __restrict__ out,           // (B,10)
    int B)
{
    __shared__ float xs[IPB * 900];            // 4 padded images, 14.4 KB
    __shared__ float red[IPB][NWAVE][10];      // wave partials, 2 KB

    const int tid      = threadIdx.x;
    const int img_base = blockIdx.x * IPB;

    // Stage up to 4 zero-padded 30x30 images; zero the reduction table.
    for (int i = tid; i < IPB * 900; i += NTHR) {
        int s = i / 900;
        int j = i - s * 900;
        int img = img_base + s;
        float v = 0.f;
        if (img < B) {
            int r = j / WP, c = j - r * WP;
            if (r >= 1 && r <= 28 && c >= 1 && c <= 28)
                v = x[(size_t)img * NPOS + (r - 1) * 28 + (c - 1)];
        }
        xs[i] = v;
    }
    if (tid < IPB * NWAVE * 10)
        ((float*)red)[tid] = 0.f;
    __syncthreads();

    const int img_l = tid / CELLS;             // 0..3 (4 for tail lanes)
    float fc[10];
    #pragma unroll
    for (int c = 0; c < 10; c++) fc[c] = 0.f;

    if (tid < IPB * CELLS && img_base + img_l < B) {
        const int cell = tid - img_l * CELLS;
        const int base = img_l * 900;
        const int ph = cell / 14, pw = cell - ph * 14;
        const int h0 = 2 * ph, w0 = 2 * pw;

        // 4x4 padded neighborhood covering the 4 positions' 3x3 taps.
        float nb[16];
        #pragma unroll
        for (int i = 0; i < 4; i++)
            #pragma unroll
            for (int j = 0; j < 4; j++)
                nb[i * 4 + j] = xs[base + (h0 + i) * WP + (w0 + j)];

        float hbf[4], wbf[4];
        #pragma unroll
        for (int i = 0; i < 4; i++) {
            hbf[i] = (float)(h0 + i);
            wbf[i] = (float)(w0 + i);
        }

        float acc[4][8];
        #pragma unroll
        for (int p = 0; p < 4; p++)
            #pragma unroll
            for (int o = 0; o < 8; o++) acc[p][o] = 0.f;

        #pragma unroll
        for (int k = 0; k < 9; k++) {          // deform tap
            const int kx = k / 3, ky = k % 3;
            #pragma unroll
            for (int p = 0; p < 4; p++) {      // position within pool cell
                const int dh = p >> 1, dw = p & 1;

                float offx = b_off[k], offy = b_off[k + 9];
                #pragma unroll
                for (int t = 0; t < 9; t++) {
                    float nv = nb[(dh + t / 3) * 4 + (dw + t % 3)];
                    offx = fmaf(w_off[k * 9 + t],       nv, offx);
                    offy = fmaf(w_off[(k + 9) * 9 + t], nv, offy);
                }

                float p_x = hbf[dh + kx] + offx;
                float p_y = wbf[dw + ky] + offy;

                float q0x = floorf(p_x), q0y = floorf(p_y);
                float qltx = fminf(fmaxf(q0x,       0.f), 29.f);
                float qlty = fminf(fmaxf(q0y,       0.f), 29.f);
                float qrbx = fminf(fmaxf(q0x + 1.f, 0.f), 29.f);
                float qrby = fminf(fmaxf(q0y + 1.f, 0.f), 29.f);
                float px   = fminf(fmaxf(p_x,       0.f), 29.f);
                float py   = fminf(fmaxf(p_y,       0.f), 29.f);

                float gltx = 1.f + (qltx - px);
                float glty = 1.f + (qlty - py);
                float grbx = 1.f - (qrbx - px);
                float grby = 1.f - (qrby - py);

                int rl = base + (int)qltx * WP;   // row bases as int indices
                int rr = base + (int)qrbx * WP;
                int ily = (int)qlty, iry = (int)qrby;

                float s = gltx * (glty * xs[rl + ily] + grby * xs[rl + iry])
                        + grbx * (glty * xs[rr + ily] + grby * xs[rr + iry]);

                #pragma unroll
                for (int o = 0; o < 8; o++)
                    acc[p][o] = fmaf(w_conv[o * 9 + k], s, acc[p][o]);
            }
        }

        // relu + 2x2 maxpool in registers.
        float m[8];
        #pragma unroll
        for (int o = 0; o < 8; o++)
            m[o] = fmaxf(fmaxf(fmaxf(acc[0][o], acc[1][o]),
                               fmaxf(acc[2][o], acc[3][o])), 0.f);

        // FC partials.
        #pragma unroll
        for (int c = 0; c < 10; c++) {
            const float* wr = w_fc + c * NPOOL + cell;
            #pragma unroll
            for (int o = 0; o < 8; o++)
                fc[c] = fmaf(m[o], wr[o * CELLS], fc[c]);
        }
        if (cell == 0) {          // fold bias exactly once per image
            #pragma unroll
            for (int c = 0; c < 10; c++) fc[c] += b_fc[c];
        }
    }

    // Per-wave segmented butterfly (a 64-lane wave spans <=2 images),
    // lane 0 writes partials to the LDS table. No atomics.
    const int lane = tid & 63;
    const int w    = tid >> 6;
    const int seg0 = (w * 64) / CELLS;
    const int seg1 = (w * 64 + 63) / CELLS;

    if (seg0 == seg1) {
        #pragma unroll
        for (int c = 0; c < 10; c++) {
            float v = fc[c];
            #pragma unroll
            for (int sh = 32; sh > 0; sh >>= 1) v += __shfl_down(v, sh, 64);
            if (lane == 0) red[seg0][w][c] = v;
        }
    } else {
        const bool in0 = (img_l == seg0);
        #pragma unroll
        for (int c = 0; c < 10; c++) {
            float v0 = in0 ? fc[c] : 0.f;
            float v1 = fc[c] - v0;
            #pragma unroll
            for (int sh = 32; sh > 0; sh >>= 1) {
                v0 += __shfl_down(v0, sh, 64);
                v1 += __shfl_down(v1, sh, 64);
            }
            if (lane == 0) {
                red[seg0][w][c] = v0;
                if (seg1 < IPB) red[seg1][w][c] = v1;
            }
        }
    }
    __syncthreads();

    // Final: 40 threads, one (image, class) each; plain store.
    if (tid < IPB * 10) {
        int il = tid / 10, c = tid - il * 10;
        int img = img_base + il;
        if (img < B) {
            float a = 0.f;
            #pragma unroll
            for (int ww = 0; ww < NWAVE; ww++) a += red[il][ww][c];
            out[img * 10 + c] = a;
        }
    }
}

extern "C" void kernel_launch(void* const* d_in, const int* in_sizes, int n_in,
                              void* d_out, int out_size, void* d_ws, size_t ws_size,
                              hipStream_t stream) {
    const float* x      = (const float*)d_in[0];
    const float* w_off  = (const float*)d_in[1];
    const float* b_off  = (const float*)d_in[2];
    const float* w_conv = (const float*)d_in[3];
    const float* w_fc   = (const float*)d_in[4];
    const float* b_fc   = (const float*)d_in[5];
    float* out = (float*)d_out;

    const int B = in_sizes[0] / NPOS;
    const int grid = (B + IPB - 1) / IPB;
    deform_net_kernel<<<grid, NTHR, 0, stream>>>(x, w_off, b_off, w_conv,
                                                 w_fc, b_fc, out, B);
}

// Round 7
// 126.821 us; speedup vs baseline: 1.5056x; 1.5056x over previous
//
#include <hip/hip_runtime.h>

// Fused deformable-conv net — round-2 structure (measured best: 75 us,
// 68 VGPR, 92% VALUBusy), with exactly two changes:
//  1. w_off/b_off/w_conv staged to LDS: broadcast ds_read_b32 with
//     immediate offsets replaces per-lane global loads + 64-bit addr math
//     in the hot (k,p) loop.
//  2. factored bilinear combine (6 VALU vs 8, identical clip semantics).
// Structure lessons (r3-r6): any flat/packed restructure of this body
// compiles to a 40-44 VGPR schedule with ~1.5x the instructions. Keep:
// 256-thr blocks, one image/block, if(tid<196), k-outer/p-inner acc[4][8],
// direct xs[int] indexing, no launch-bounds min, no global atomics.

#define HH 28
#define WW 28
#define WP 30
#define NPOS 784
#define NPOOL 1568
#define CELLS 196

__global__ __launch_bounds__(256) void deform_net_kernel(
    const float* __restrict__ x,       // (B,1,28,28)
    const float* __restrict__ w_off,   // (18,1,3,3)
    const float* __restrict__ b_off,   // (18,)
    const float* __restrict__ w_conv,  // (8,1,3,3)
    const float* __restrict__ w_fc,    // (10,1568)
    const float* __restrict__ b_fc,    // (10,)
    float* __restrict__ out)           // (B,10)
{
    __shared__ float xs[900];          // padded image
    __shared__ float wo_s[162];        // w_off
    __shared__ float bo_s[18];         // b_off
    __shared__ float wc_s[72];         // w_conv
    __shared__ float red[4][10];

    const int b   = blockIdx.x;
    const int tid = threadIdx.x;

    if (tid < 162) wo_s[tid] = w_off[tid];
    if (tid < 18)  bo_s[tid] = b_off[tid];
    if (tid < 72)  wc_s[tid] = w_conv[tid];

    // Stage zero-padded image into LDS.
    const float* xb = x + (size_t)b * NPOS;
    for (int i = tid; i < 900; i += 256) {
        int r = i / WP, c = i % WP;
        float v = 0.f;
        if (r >= 1 && r <= HH && c >= 1 && c <= WW)
            v = xb[(r - 1) * WW + (c - 1)];
        xs[i] = v;
    }
    __syncthreads();

    float fc[10];
    #pragma unroll
    for (int c = 0; c < 10; c++) fc[c] = 0.f;

    if (tid < CELLS) {
        const int ph = tid / 14, pw = tid % 14;   // pool cell coords
        const int h0 = 2 * ph, w0 = 2 * pw;       // top-left output position

        // 4x4 padded-image neighborhood covering all 4 positions' 3x3 taps.
        float nb[16];
        #pragma unroll
        for (int i = 0; i < 4; i++)
            #pragma unroll
            for (int j = 0; j < 4; j++)
                nb[i * 4 + j] = xs[(h0 + i) * WP + (w0 + j)];

        float acc[4][8];
        #pragma unroll
        for (int p = 0; p < 4; p++)
            #pragma unroll
            for (int o = 0; o < 8; o++) acc[p][o] = 0.f;

        #pragma unroll
        for (int k = 0; k < 9; k++) {          // deform tap
            const int kx = k / 3, ky = k % 3;
            #pragma unroll
            for (int p = 0; p < 4; p++) {      // position within pool cell
                const int dh = p >> 1, dw = p & 1;

                // offset channels k (x) and k+9 (y): 3x3 conv at (h0+dh, w0+dw)
                float offx = bo_s[k], offy = bo_s[k + 9];
                #pragma unroll
                for (int t = 0; t < 9; t++) {
                    float nv = nb[(dh + t / 3) * 4 + (dw + t % 3)];
                    offx = fmaf(wo_s[k * 9 + t],       nv, offx);
                    offy = fmaf(wo_s[(k + 9) * 9 + t], nv, offy);
                }

                // sample coords in padded frame: p0=(h+1,w+1), pn=(kx-1,ky-1)
                float p_x = (float)(h0 + dh + kx) + offx;
                float p_y = (float)(w0 + dw + ky) + offy;

                float q0x = floorf(p_x), q0y = floorf(p_y);
                float qltx = fminf(fmaxf(q0x,       0.f), 29.f);
                float qlty = fminf(fmaxf(q0y,       0.f), 29.f);
                float qrbx = fminf(fmaxf(q0x + 1.f, 0.f), 29.f);
                float qrby = fminf(fmaxf(q0y + 1.f, 0.f), 29.f);
                float px   = fminf(fmaxf(p_x,       0.f), 29.f);
                float py   = fminf(fmaxf(p_y,       0.f), 29.f);

                float gltx = 1.f + (qltx - px);
                float glty = 1.f + (qlty - py);
                float grbx = 1.f - (qrbx - px);
                float grby = 1.f - (qrby - py);

                int ilx = (int)qltx, ily = (int)qlty;
                int irx = (int)qrbx, iry = (int)qrby;

                float xlt = xs[ilx * WP + ily];
                float xrb = xs[irx * WP + iry];
                float xlb = xs[ilx * WP + iry];
                float xrt = xs[irx * WP + ily];

                // factored bilinear combine (same clip semantics)
                float s = gltx * (glty * xlt + grby * xlb)
                        + grbx * (glty * xrt + grby * xrb);

                #pragma unroll
                for (int o = 0; o < 8; o++)
                    acc[p][o] = fmaf(wc_s[o * 9 + k], s, acc[p][o]);
            }
        }

        // relu + 2x2 maxpool in registers, then FC partial sums.
        #pragma unroll
        for (int o = 0; o < 8; o++) {
            float m = fmaxf(fmaxf(acc[0][o], acc[1][o]),
                            fmaxf(acc[2][o], acc[3][o]));
            m = fmaxf(m, 0.f);
            const float* wrow = w_fc + o * CELLS + tid;  // flat idx o*196+cell
            #pragma unroll
            for (int c = 0; c < 10; c++)
                fc[c] = fmaf(m, wrow[c * NPOOL], fc[c]);
        }
    }

    // Wave (64-lane) shuffle reduce, then cross-wave via LDS.
    #pragma unroll
    for (int c = 0; c < 10; c++) {
        #pragma unroll
        for (int sh = 32; sh > 0; sh >>= 1)
            fc[c] += __shfl_down(fc[c], sh, 64);
    }
    const int wave = tid >> 6, lane = tid & 63;
    if (lane == 0) {
        #pragma unroll
        for (int c = 0; c < 10; c++) red[wave][c] = fc[c];
    }
    __syncthreads();
    if (tid < 10)
        out[b * 10 + tid] = red[0][tid] + red[1][tid] + red[2][tid]
                          + red[3][tid] + b_fc[tid];
}

extern "C" void kernel_launch(void* const* d_in, const int* in_sizes, int n_in,
                              void* d_out, int out_size, void* d_ws, size_t ws_size,
                              hipStream_t stream) {
    const float* x      = (const float*)d_in[0];
    const float* w_off  = (const float*)d_in[1];
    const float* b_off  = (const float*)d_in[2];
    const float* w_conv = (const float*)d_in[3];
    const float* w_fc   = (const float*)d_in[4];
    const float* b_fc   = (const float*)d_in[5];
    float* out = (float*)d_out;

    const int B = in_sizes[0] / NPOS;
    deform_net_kernel<<<B, 256, 0, stream>>>(x, w_off, b_off, w_conv, w_fc, b_fc, out);
}